// Round 13
// baseline (212.723 us; speedup 1.0000x reference)
//
#include <hip/hip_runtime.h>
#include <hip/hip_bf16.h>

#define TOTAL   4194304    // 16*256*32*32
#define NK      2098u      // ceil(0.0005*TOTAL)
#define NPOS    16384      // 16*32*32
#define ACAP    1048576u   // append buffer capacity (4 MB region)

typedef _Float16 fp16x4 __attribute__((ext_vector_type(4)));
typedef __fp16   fp16r2 __attribute__((ext_vector_type(2)));   // cvt_pkrtz return type
typedef float    f32x4  __attribute__((ext_vector_type(4)));

// ---- shared find: k-th largest over a histogram (suffix-sum radix pick) ------
__device__ __forceinline__ void find_in_lds(const unsigned* h, int nbins, int level,
                                            unsigned kth, uint2* ctrl, float* thr) {
  __shared__ unsigned part[256];
  __shared__ int sel;
  int t = threadIdx.x;
  int per = nbins >> 8;
  unsigned s = 0;
  for (int i = 0; i < per; i++) s += h[t * per + i];
  part[t] = s;
  __syncthreads();
  for (int off = 1; off < 256; off <<= 1) {
    unsigned add = (t + off < 256) ? part[t + off] : 0u;
    __syncthreads();
    part[t] += add;
    __syncthreads();
  }
  if ((part[t] >= kth) && (t == 255 || part[t + 1] < kth)) sel = t;
  __syncthreads();
  if (t == 0) {
    int c = sel;
    unsigned cum = (c < 255) ? part[c + 1] : 0u;
    for (int i = per - 1; i >= 0; --i) {
      unsigned hv = h[c * per + i];
      if (cum + hv >= kth) {
        ctrl[level].x = (unsigned)(c * per + i);
        ctrl[level].y = kth - cum;
        break;
      }
      cum += hv;
    }
    if (level == 2) {
      unsigned bits = (ctrl[0].x << 20) | (ctrl[1].x << 8) | ctrl[2].x;
      *thr = __uint_as_float(bits);
    }
  }
  __syncthreads();
}

// ---------------- conv 9x9, 1->256ch, ReLU, output A[b][y*32+x][c] -------------
__launch_bounds__(256)
__global__ void conv_kernel(const float* __restrict__ x, const float* __restrict__ w,
                            float* __restrict__ A) {
  int b = blockIdx.x >> 5;      // 16
  int y = blockIdx.x & 31;      // 32
  int c = threadIdx.x;          // 256
  const float* xb = x + b * 1024;
  const float* wc = w + c * 81;
  float acc[32];
#pragma unroll
  for (int i = 0; i < 32; i++) acc[i] = 0.f;
#pragma unroll
  for (int dy = 0; dy < 9; ++dy) {
    int yy = y + dy - 4;
    if (yy < 0 || yy >= 32) continue;      // uniform per block
    float wv[9];
#pragma unroll
    for (int dx = 0; dx < 9; ++dx) wv[dx] = wc[dy * 9 + dx];
    const float* xr = xb + yy * 32;
#pragma unroll
    for (int ix = 0; ix < 32; ++ix) {
      float xv = xr[ix];                   // uniform -> scalar load
#pragma unroll
      for (int dx = 0; dx < 9; ++dx) {
        int ox = ix + 4 - dx;
        if (ox >= 0 && ox < 32) acc[ox] += wv[dx] * xv;
      }
    }
  }
  float* Arow = A + ((b * 32 + y) * 32) * 256 + c;
#pragma unroll
  for (int ox = 0; ox < 32; ++ox) {
    float v = acc[ox] > 0.f ? acc[ox] : 0.f;
    Arow[ox * 256] = v;
  }
}

// ---------------- level-1 histogram (2048 exponent bins, LDS-staged) -----------
__launch_bounds__(256)
__global__ void hist1_kernel(const float* __restrict__ A, unsigned* __restrict__ hist) {
  __shared__ unsigned h[2048];
  for (int i = threadIdx.x; i < 2048; i += 256) h[i] = 0;
  __syncthreads();
  int stride = gridDim.x * blockDim.x;
  unsigned z = 0;
  for (int i = blockIdx.x * blockDim.x + threadIdx.x; i < TOTAL / 4; i += stride) {
    float4 f = ((const float4*)A)[i];
    unsigned u;
    u = __float_as_uint(f.x); if (u) atomicAdd(&h[u >> 20], 1u); else z++;
    u = __float_as_uint(f.y); if (u) atomicAdd(&h[u >> 20], 1u); else z++;
    u = __float_as_uint(f.z); if (u) atomicAdd(&h[u >> 20], 1u); else z++;
    u = __float_as_uint(f.w); if (u) atomicAdd(&h[u >> 20], 1u); else z++;
  }
  if (z) atomicAdd(&h[0], z);
  __syncthreads();
  for (int i = threadIdx.x; i < 2048; i += 256) if (h[i]) atomicAdd(&hist[i], h[i]);
}

// ---------------- find level 1 (single block over global 2048-bin hist) --------
__launch_bounds__(256)
__global__ void find_kernel(const unsigned* __restrict__ hist, uint2* __restrict__ ctrl,
                            float* __restrict__ thr) {
  find_in_lds(hist, 2048, 0, NK, ctrl, thr);
}

// ---- append: collect low-20-bits of elements whose top-12-bits == B1 ----------
// Only hist1[B1] elements match (the k-th-largest boundary bin, ~few thousand).
__launch_bounds__(256)
__global__ void append_kernel(const float* __restrict__ A, const uint2* __restrict__ ctrl,
                              unsigned* __restrict__ buf, unsigned* __restrict__ cnt) {
  unsigned B1 = ctrl[0].x;
  int stride = gridDim.x * blockDim.x;
  for (int i = blockIdx.x * blockDim.x + threadIdx.x; i < TOTAL / 4; i += stride) {
    float4 f = ((const float4*)A)[i];
    unsigned u;
    u = __float_as_uint(f.x);
    if ((u >> 20) == B1) { unsigned p = atomicAdd(cnt, 1u); if (p < ACAP) buf[p] = u & 0xFFFFF; }
    u = __float_as_uint(f.y);
    if ((u >> 20) == B1) { unsigned p = atomicAdd(cnt, 1u); if (p < ACAP) buf[p] = u & 0xFFFFF; }
    u = __float_as_uint(f.z);
    if ((u >> 20) == B1) { unsigned p = atomicAdd(cnt, 1u); if (p < ACAP) buf[p] = u & 0xFFFFF; }
    u = __float_as_uint(f.w);
    if ((u >> 20) == B1) { unsigned p = atomicAdd(cnt, 1u); if (p < ACAP) buf[p] = u & 0xFFFFF; }
  }
}

// ---- final select: levels 2+3 over the appended candidates (one block) --------
__launch_bounds__(256)
__global__ void findfin_kernel(const unsigned* __restrict__ buf, const unsigned* __restrict__ cnt,
                               uint2* __restrict__ ctrl, float* __restrict__ thr) {
  __shared__ unsigned h[4096];
  int t = threadIdx.x;
  for (int i = t; i < 4096; i += 256) h[i] = 0;
  __syncthreads();
  unsigned N = *cnt; if (N > ACAP) N = ACAP;
  unsigned kth1 = ctrl[0].y;
  for (unsigned i = t; i < N; i += 256) atomicAdd(&h[(buf[i] >> 8) & 0xFFF], 1u);
  __syncthreads();
  find_in_lds(h, 4096, 1, kth1, ctrl, thr);
  unsigned b2 = ctrl[1].x, kth2 = ctrl[1].y;   // visible: thread0 wrote + barrier in helper
  h[t < 256 ? t : 0] = (t < 256) ? 0u : h[0];
  if (t < 256) h[t] = 0;
  __syncthreads();
  for (unsigned i = t; i < N; i += 256)
    if (((buf[i] >> 8) & 0xFFF) == b2) atomicAdd(&h[buf[i] & 0xFF], 1u);
  __syncthreads();
  find_in_lds(h, 256, 2, kth2, ctrl, thr);
}

// ---------------- per-position top-3 (one wave per position) ------------------
__launch_bounds__(256)
__global__ void top3_kernel(const float* __restrict__ A, const float* __restrict__ thrp,
                            float* __restrict__ t3v, int* __restrict__ t3i) {
  int gid = blockIdx.x * blockDim.x + threadIdx.x;
  int wid = gid >> 6, lane = gid & 63;
  float thr = *thrp;
  float4 av = *(const float4*)&A[wid * 256 + lane * 4];
  float va[4] = {av.x, av.y, av.z, av.w};
  float v0 = -1.f, v1 = -1.f, v2 = -1.f;
  int i0 = 0, i1 = 0, i2 = 0;
#pragma unroll
  for (int j = 0; j < 4; j++) {
    float val = (va[j] >= thr) ? va[j] : 0.f;
    int idx = lane * 4 + j;
    if (val > v0)      { v2 = v1; i2 = i1; v1 = v0; i1 = i0; v0 = val; i0 = idx; }
    else if (val > v1) { v2 = v1; i2 = i1; v1 = val; i1 = idx; }
    else if (val > v2) { v2 = val; i2 = idx; }
  }
#pragma unroll
  for (int off = 1; off < 64; off <<= 1) {
    float b0 = __shfl_xor(v0, off), b1 = __shfl_xor(v1, off), b2 = __shfl_xor(v2, off);
    int   j0 = __shfl_xor(i0, off), j1 = __shfl_xor(i1, off), j2 = __shfl_xor(i2, off);
    float a0 = v0, a1 = v1, a2 = v2;
    int   x0 = i0, x1 = i1, x2 = i2;
    float rv[3]; int ri[3];
#pragma unroll
    for (int r = 0; r < 3; r++) {
      bool ta = (a0 > b0) || (a0 == b0 && x0 < j0);
      rv[r] = ta ? a0 : b0; ri[r] = ta ? x0 : j0;
      if (ta) { a0 = a1; x0 = x1; a1 = a2; x1 = x2; a2 = -1.f; x2 = 1 << 29; }
      else    { b0 = b1; j0 = j1; b1 = b2; j1 = j2; b2 = -1.f; j2 = 1 << 29; }
    }
    v0 = rv[0]; v1 = rv[1]; v2 = rv[2];
    i0 = ri[0]; i1 = ri[1]; i2 = ri[2];
  }
  if (lane == 0) {
    t3v[wid * 3] = v0; t3v[wid * 3 + 1] = v1; t3v[wid * 3 + 2] = v2;
    t3i[wid * 3] = i0; t3i[wid * 3 + 1] = i1; t3i[wid * 3 + 2] = i2;
  }
}

// ------- per-batch global max from t3v (16 blocks) + pe table (same grid) -----
__launch_bounds__(256)
__global__ void gmax_kernel(const float* __restrict__ t3v, float* __restrict__ gmax,
                            float* __restrict__ pe) {
  __shared__ float wm[4];
  int b = blockIdx.x, t = threadIdx.x;
  {   // fused pe fill: 16 blocks x 256 = 4096 entries
    int id = b * 256 + t;
    int w = id >> 7, d = id & 127;
    int i = d >> 1;
    float ang = (float)w * __expf(-(float)i * (logf(10000.f) / 64.f));
    pe[id] = (d & 1) ? cosf(ang) : sinf(ang);
  }
  float m = 0.f;
#pragma unroll
  for (int i = 0; i < 4; i++) {
    int p = (b << 10) + i * 256 + t;
    m = fmaxf(m, t3v[p * 3]);
  }
#pragma unroll
  for (int off = 1; off < 64; off <<= 1) m = fmaxf(m, __shfl_xor(m, off));
  if ((t & 63) == 0) wm[t >> 6] = m;
  __syncthreads();
  if (t == 0) gmax[b] = fmaxf(fmaxf(wm[0], wm[1]), fmaxf(wm[2], wm[3]));
}

// ---------------- sparse_weights (full rows) + top_idx + loc ------------------
__launch_bounds__(256)
__global__ void scatter_loc_kernel(const float* __restrict__ t3v, const int* __restrict__ t3i,
                                   const float* __restrict__ gmax,
                                   const float* __restrict__ pe, const float* __restrict__ emb,
                                   float* __restrict__ out_sw, float* __restrict__ out_idx,
                                   float* __restrict__ loc) {
  int t = threadIdx.x;
  int p = blockIdx.x * 2 + (t >> 7);
  int d = t & 127;
  int b = p >> 10;
  float g = gmax[b];
  float denom = (g == 0.f) ? 1.f : g;
  float v0 = t3v[p * 3], v1 = t3v[p * 3 + 1];
  int i0 = t3i[p * 3], i1 = t3i[p * 3 + 1];
  float sw0 = v0 / denom, sw1 = v1 / denom;
  float a = pe[(p & 31) * 128 + d];
  if (v0 > 0.f) a += sw0 * emb[i0 * 128 + d];
  if (v1 > 0.f) a += sw1 * emb[i1 * 128 + d];
  loc[p * 128 + d] = a;
  // full sparse_weights row (zeros + the two scattered values) -> no memset
  int c = d * 2;
  float2 sw;
  sw.x = (c == i0) ? sw0 : (c == i1) ? sw1 : 0.f;
  sw.y = (c + 1 == i0) ? sw0 : (c + 1 == i1) ? sw1 : 0.f;
  *(float2*)&out_sw[(size_t)p * 256 + c] = sw;
  if (d == 0) {
    out_idx[p * 3 + 0] = (float)t3i[p * 3 + 0];
    out_idx[p * 3 + 1] = (float)t3i[p * 3 + 1];
    out_idx[p * 3 + 2] = (float)t3i[p * 3 + 2];
  }
}

// ---------------- qkv GEMM (MFMA f16): C[j][pos] = ipw . loc^T ----------------
// Q pre-scaled by 0.25*log2(e) -> attention scores land in log2 domain.
#define QSCALE 0.36067376f   // 0.25 * 1.4426950408889634
__launch_bounds__(256)
__global__ void qkv_gemm(const float* __restrict__ ipw, const float* __restrict__ loc,
                         const float* __restrict__ bias,
                         _Float16* __restrict__ Qh, _Float16* __restrict__ Kh,
                         _Float16* __restrict__ Vt) {
  __shared__ _Float16 Aw[64][136];   // [j_local][k]   272B pitch (16B-mult)
  __shared__ _Float16 Bl[64][136];   // [pos_local][k]
  __shared__ _Float16 Ts[64][72];    // V transpose [d_local][pos_local], 144B pitch
  int bid = blockIdx.x;
  int lb = (bid & 7) * 192 + (bid >> 3);       // XCD swizzle (1536 = 8*192)
  int jt = lb % 6;                   // j-tile: 0,1=Q 2,3=K 4,5=V
  int pt = lb / 6;                   // pos-tile 0..255 (64 pos, never crosses batch)
  int j0 = jt * 64, p0 = pt * 64;
  int t = threadIdx.x;
#pragma unroll
  for (int i = 0; i < 8; i++) {      // stage W tile: 64 j-rows x 128 k (f32->f16)
    int id = t + i * 256;
    int row = id >> 5, k4 = id & 31;
    float4 f = *(const float4*)&ipw[(j0 + row) * 128 + k4 * 4];
    *(fp16x4*)&Aw[row][k4 * 4] =
        (fp16x4){(_Float16)f.x, (_Float16)f.y, (_Float16)f.z, (_Float16)f.w};
  }
#pragma unroll
  for (int i = 0; i < 8; i++) {      // stage loc tile: 64 pos-rows x 128 k
    int id = t + i * 256;
    int row = id >> 5, k4 = id & 31;
    float4 f = *(const float4*)&loc[(size_t)(p0 + row) * 128 + k4 * 4];
    *(fp16x4*)&Bl[row][k4 * 4] =
        (fp16x4){(_Float16)f.x, (_Float16)f.y, (_Float16)f.z, (_Float16)f.w};
  }
  __syncthreads();
  int w = t >> 6, l = t & 63;
  int lr = l & 15, lg = l >> 4;      // lr = in-tile row/col, lg = k-group
  f32x4 acc[4] = {};                 // 4 pos-subtiles, wave owns j-sub = w*16
#pragma unroll
  for (int kk = 0; kk < 8; kk++) {
    int k0 = kk * 16 + lg * 4;
    fp16x4 a = *(const fp16x4*)&Aw[w * 16 + lr][k0];
#pragma unroll
    for (int ps = 0; ps < 4; ps++) {
      fp16x4 bf = *(const fp16x4*)&Bl[ps * 16 + lr][k0];
      acc[ps] = __builtin_amdgcn_mfma_f32_16x16x16f16(a, bf, acc[ps], 0, 0, 0);
    }
  }
  // lane holds C[j = j0 + w*16 + lg*4 + r][pos = p0 + ps*16 + lr]
  int jbase = j0 + w * 16;           // 16-aligned -> one head per wave
  int b = p0 >> 10;
  int sp = p0 & 1023;
  if (jt < 4) {
    bool isQ = (jbase < 128);
    float scale = isQ ? QSCALE : 1.f;
    _Float16* dst = isQ ? Qh : Kh;
    int head = (jbase - (isQ ? 0 : 128)) >> 4;
#pragma unroll
    for (int ps = 0; ps < 4; ps++) {
      int pos = sp + ps * 16 + lr;
      fp16x4 v;
#pragma unroll
      for (int r = 0; r < 4; r++)
        v[r] = (_Float16)((acc[ps][r] + bias[jbase + lg * 4 + r]) * scale);
      *(fp16x4*)&dst[(size_t)(((b * 8 + head) << 10) + pos) * 16 + lg * 4] = v;
    }
  } else {
    // V: scatter into Ts[d_local][pos_local], then coalesced row writes to Vt
#pragma unroll
    for (int ps = 0; ps < 4; ps++) {
#pragma unroll
      for (int r = 0; r < 4; r++)
        Ts[w * 16 + lg * 4 + r][ps * 16 + lr] =
            (_Float16)(acc[ps][r] + bias[jbase + lg * 4 + r]);
    }
    __syncthreads();
    int dl = t >> 2, seg = t & 3;
    int vcol = (j0 - 256) + dl;      // 0..127
    int head = vcol >> 4, d = vcol & 15;
    float4 w0 = *(float4*)&Ts[dl][seg * 16];
    float4 w1 = *(float4*)&Ts[dl][seg * 16 + 8];
    _Float16* dp = &Vt[(size_t)(((b * 8 + head) * 16 + d) << 10) + sp + seg * 16];
    *(float4*)dp = w0;
    *(float4*)(dp + 8) = w1;
  }
}

// ---------------- MFMA flash attention (exp2-domain, sc[8] halves) ------------
// Scores in log2 domain (Q pre-scaled by 0.25*log2e): p = exp2(s - m).
// sc[8] (32 VGPR) instead of sc[16] -> occupancy recovery vs R12.
#define KP 24    // Kl pitch (halves): 48B rows -> 2-way LDS (free)
#define VP 264   // Vl pitch (halves): 528B rows, 16B-aligned
__launch_bounds__(256)
__global__ void attn_kernel(const _Float16* __restrict__ Qh, const _Float16* __restrict__ Kh,
                            const _Float16* __restrict__ Vt, float* __restrict__ ctx) {
  __shared__ _Float16 Kl[256][KP];
  __shared__ _Float16 Vl[16][VP];
  int bid = blockIdx.x;
  int lb = ((bid & 7) << 8) | (bid >> 3);   // XCD swizzle: same-(b,h) on one XCD
  int qt = lb & 15;
  int h  = (lb >> 4) & 7;
  int b  = lb >> 7;
  int bh = b * 8 + h;
  int t  = threadIdx.x;
  int w  = t >> 6, l = t & 63;
  int ql = l & 15, g = l >> 4;

  int qbase = qt * 64 + w * 16;
  fp16x4 bq = *(const fp16x4*)&Qh[(size_t)((bh << 10) + qbase + ql) * 16 + g * 4];

  float m = -1e30f, lsum = 0.f;
  f32x4 acc = {0.f, 0.f, 0.f, 0.f};

  for (int kc = 0; kc < 4; ++kc) {
    __syncthreads();
    {   // stage K rows (1 key/thread, 32B) + Vt rows (d = t>>4, 16 keys/thread)
      const float4* kp = (const float4*)&Kh[(size_t)((bh << 10) + kc * 256 + t) * 16];
      float4 a0 = kp[0], a1 = kp[1];
      *(float4*)&Kl[t][0] = a0;
      *(float4*)&Kl[t][8] = a1;
      int d = t >> 4, seg = t & 15;
      const float4* vp = (const float4*)&Vt[(size_t)((bh * 16 + d) << 10) + kc * 256 + seg * 16];
      float4 b0 = vp[0], b1 = vp[1];
      *(float4*)&Vl[d][seg * 16] = b0;
      *(float4*)&Vl[d][seg * 16 + 8] = b1;
    }
    __syncthreads();
#pragma unroll
    for (int half = 0; half < 2; ++half) {
      f32x4 sc[8];
      float cm = -1e30f;
#pragma unroll
      for (int ts = 0; ts < 8; ++ts) {
        int tile = half * 8 + ts;
        fp16x4 ka = *(const fp16x4*)&Kl[tile * 16 + ql][g * 4];
        sc[ts] = __builtin_amdgcn_mfma_f32_16x16x16f16(ka, bq,
                   (f32x4){0.f, 0.f, 0.f, 0.f}, 0, 0, 0);
        cm = fmaxf(cm, fmaxf(fmaxf(sc[ts][0], sc[ts][1]), fmaxf(sc[ts][2], sc[ts][3])));
      }
      cm = fmaxf(cm, __shfl_xor(cm, 16));
      cm = fmaxf(cm, __shfl_xor(cm, 32));
      if (!__all(cm <= m + 11.5f)) {     // defer-max, log2 units (2^11.5 ~ e^8)
        float mn = fmaxf(m, cm);
        float scl = __builtin_amdgcn_exp2f(m - mn);
        lsum *= scl;
        acc[0] *= __shfl(scl, g * 4 + 0);
        acc[1] *= __shfl(scl, g * 4 + 1);
        acc[2] *= __shfl(scl, g * 4 + 2);
        acc[3] *= __shfl(scl, g * 4 + 3);
        m = mn;
      }
#pragma unroll
      for (int ts = 0; ts < 8; ++ts) {
        int tile = half * 8 + ts;
        float p0 = __builtin_amdgcn_exp2f(sc[ts][0] - m);
        float p1 = __builtin_amdgcn_exp2f(sc[ts][1] - m);
        float p2 = __builtin_amdgcn_exp2f(sc[ts][2] - m);
        float p3 = __builtin_amdgcn_exp2f(sc[ts][3] - m);
        lsum += (p0 + p1) + (p2 + p3);
        union { fp16r2 h2[2]; fp16x4 h4; } u;
        u.h2[0] = __builtin_amdgcn_cvt_pkrtz(p0, p1);
        u.h2[1] = __builtin_amdgcn_cvt_pkrtz(p2, p3);
        fp16x4 vb = *(const fp16x4*)&Vl[ql][tile * 16 + g * 4];
        acc = __builtin_amdgcn_mfma_f32_16x16x16f16(u.h4, vb, acc, 0, 0, 0);
      }
    }
  }
  lsum += __shfl_xor(lsum, 16);
  lsum += __shfl_xor(lsum, 32);
  float inv = 1.f / lsum;
  float* cp = ctx + (size_t)((b << 10) + qbase) * 128 + h * 16;
#pragma unroll
  for (int r = 0; r < 4; ++r) {    // acc[r]: q = 4g+r, d = ql
    float o = acc[r] * __shfl(inv, g * 4 + r);
    cp[(g * 4 + r) * 128 + ql] = o;
  }
}

// ---------------- mean over sequence + out_proj -------------------------------
__launch_bounds__(128)
__global__ void mean_kernel(const float* __restrict__ ctx, float* __restrict__ cmean) {
  int b = blockIdx.x >> 3, sc = blockIdx.x & 7, d = threadIdx.x;
  float s = 0.f;
  for (int i = 0; i < 128; i++) s += ctx[((b << 10) + sc * 128 + i) * 128 + d];
  atomicAdd(&cmean[b * 128 + d], s);
}

__launch_bounds__(256)
__global__ void pooled_kernel(const float* __restrict__ cm, const float* __restrict__ W,
                              const float* __restrict__ bias, float* __restrict__ out) {
  int id = blockIdx.x * 256 + threadIdx.x;   // 2048
  int b = id >> 7, d = id & 127;
  float s = bias[d];
  const float sc = 1.f / 1024.f;
  for (int k = 0; k < 128; k++) s += cm[b * 128 + k] * sc * W[d * 128 + k];
  out[id] = s;
}

extern "C" void kernel_launch(void* const* d_in, const int* in_sizes, int n_in,
                              void* d_out, int out_size, void* d_ws, size_t ws_size,
                              hipStream_t stream) {
  (void)in_sizes; (void)n_in; (void)out_size;
  if (ws_size < 34400000) return;   // need ~34.3 MB scratch

  const float* x   = (const float*)d_in[0];
  const float* cw  = (const float*)d_in[1];
  const float* emb = (const float*)d_in[2];
  const float* ipw = (const float*)d_in[3];
  const float* ipb = (const float*)d_in[4];
  const float* opw = (const float*)d_in[5];
  const float* opb = (const float*)d_in[6];

  char* ws = (char*)d_ws;
  float*     A    = (float*)(ws + 0);           // 16.78 MB, dead after top3
  _Float16*  Vt   = (_Float16*)(ws + 0);        // 4.19 MB, overwrites A
  float*     ctx  = (float*)(ws + 4194304);     // 8.39 MB (after top3)
  float*     loc  = (float*)(ws + 16777216);    // 8.39 MB (after find phase)
  _Float16*  Qh   = (_Float16*)(ws + 25165824); // 4.19 MB (after find phase)
  unsigned*  abuf = (unsigned*)(ws + 25165824); // 4 MB append buffer (radix phase only)
  _Float16*  Kh   = (_Float16*)(ws + 29360128); // 4.19 MB
  char* ctrlb = ws + 33554432;                 // 64 KB control block (memset 0)
  unsigned* h1    = (unsigned*)(ctrlb);
  uint2*    ctrl  = (uint2*)(ctrlb + 25600);
  float*    thr   = (float*)(ctrlb + 25632);
  float*    gmax  = (float*)(ctrlb + 25664);
  float*    cmean = (float*)(ctrlb + 25728);
  unsigned* acnt  = (unsigned*)(ctrlb + 33920);
  float* pe  = (float*)(ws + 33554432 + 65536);
  float* t3v = (float*)(ws + 33554432 + 65536 + 16384);
  int*   t3i = (int*)  (ws + 33554432 + 65536 + 16384 + 196608);

  float* out_pooled = (float*)d_out;                   // 2048
  float* out_sw     = out_pooled + 2048;               // 4194304 (fully written)
  float* out_idx    = out_pooled + 2048 + 4194304;     // 49152  (fully written)

  hipMemsetAsync(ctrlb, 0, 65536, stream);

  conv_kernel<<<512, 256, 0, stream>>>(x, cw, A);
  hist1_kernel<<<256, 256, 0, stream>>>(A, h1);
  find_kernel<<<1, 256, 0, stream>>>(h1, ctrl, thr);
  append_kernel<<<256, 256, 0, stream>>>(A, ctrl, abuf, acnt);
  findfin_kernel<<<1, 256, 0, stream>>>(abuf, acnt, ctrl, thr);
  top3_kernel<<<4096, 256, 0, stream>>>(A, thr, t3v, t3i);
  gmax_kernel<<<16, 256, 0, stream>>>(t3v, gmax, pe);
  scatter_loc_kernel<<<8192, 256, 0, stream>>>(t3v, t3i, gmax, pe, emb, out_sw, out_idx, loc);
  qkv_gemm<<<1536, 256, 0, stream>>>(ipw, loc, ipb, Qh, Kh, Vt);
  attn_kernel<<<2048, 256, 0, stream>>>(Qh, Kh, Vt, ctx);
  mean_kernel<<<128, 128, 0, stream>>>(ctx, cmean);
  pooled_kernel<<<8, 256, 0, stream>>>(cmean, opw, opb, out_pooled);
}

// Round 14
// 191.907 us; speedup vs baseline: 1.1085x; 1.1085x over previous
//
#include <hip/hip_runtime.h>
#include <hip/hip_bf16.h>

#define TOTAL   4194304    // 16*256*32*32
#define NK      2098u      // ceil(0.0005*TOTAL)
#define NPOS    16384      // 16*32*32
#define ACAP    1048576u   // append buffer capacity (4 MB region)

typedef _Float16 fp16x4 __attribute__((ext_vector_type(4)));
typedef __fp16   fp16r2 __attribute__((ext_vector_type(2)));   // cvt_pkrtz return type
typedef float    f32x4  __attribute__((ext_vector_type(4)));

// ---- shared find: k-th largest over a histogram (suffix-sum radix pick) ------
// Ends with __syncthreads(): safe for back-to-back use in one kernel.
__device__ __forceinline__ void find_in_lds(const unsigned* h, int nbins, int level,
                                            unsigned kth, uint2* ctrl, float* thr) {
  __shared__ unsigned part[256];
  __shared__ int sel;
  int t = threadIdx.x;
  int per = nbins >> 8;
  unsigned s = 0;
  for (int i = 0; i < per; i++) s += h[t * per + i];
  part[t] = s;
  __syncthreads();
  for (int off = 1; off < 256; off <<= 1) {
    unsigned add = (t + off < 256) ? part[t + off] : 0u;
    __syncthreads();
    part[t] += add;
    __syncthreads();
  }
  if ((part[t] >= kth) && (t == 255 || part[t + 1] < kth)) sel = t;
  __syncthreads();
  if (t == 0) {
    int c = sel;
    unsigned cum = (c < 255) ? part[c + 1] : 0u;
    for (int i = per - 1; i >= 0; --i) {
      unsigned hv = h[c * per + i];
      if (cum + hv >= kth) {
        ctrl[level].x = (unsigned)(c * per + i);
        ctrl[level].y = kth - cum;
        break;
      }
      cum += hv;
    }
    if (level == 2) {
      unsigned bits = (ctrl[0].x << 20) | (ctrl[1].x << 8) | ctrl[2].x;
      *thr = __uint_as_float(bits);
    }
  }
  __syncthreads();
}

// ---------------- conv 9x9, 1->256ch, ReLU, output A[b][y*32+x][c] -------------
__launch_bounds__(256)
__global__ void conv_kernel(const float* __restrict__ x, const float* __restrict__ w,
                            float* __restrict__ A) {
  int b = blockIdx.x >> 5;      // 16
  int y = blockIdx.x & 31;      // 32
  int c = threadIdx.x;          // 256
  const float* xb = x + b * 1024;
  const float* wc = w + c * 81;
  float acc[32];
#pragma unroll
  for (int i = 0; i < 32; i++) acc[i] = 0.f;
#pragma unroll
  for (int dy = 0; dy < 9; ++dy) {
    int yy = y + dy - 4;
    if (yy < 0 || yy >= 32) continue;      // uniform per block
    float wv[9];
#pragma unroll
    for (int dx = 0; dx < 9; ++dx) wv[dx] = wc[dy * 9 + dx];
    const float* xr = xb + yy * 32;
#pragma unroll
    for (int ix = 0; ix < 32; ++ix) {
      float xv = xr[ix];                   // uniform -> scalar load
#pragma unroll
      for (int dx = 0; dx < 9; ++dx) {
        int ox = ix + 4 - dx;
        if (ox >= 0 && ox < 32) acc[ox] += wv[dx] * xv;
      }
    }
  }
  float* Arow = A + ((b * 32 + y) * 32) * 256 + c;
#pragma unroll
  for (int ox = 0; ox < 32; ++ox) {
    float v = acc[ox] > 0.f ? acc[ox] : 0.f;
    Arow[ox * 256] = v;
  }
}

// ---------------- level-1 histogram (2048 exponent bins, LDS-staged) -----------
__launch_bounds__(256)
__global__ void hist1_kernel(const float* __restrict__ A, unsigned* __restrict__ hist) {
  __shared__ unsigned h[2048];
  for (int i = threadIdx.x; i < 2048; i += 256) h[i] = 0;
  __syncthreads();
  int stride = gridDim.x * blockDim.x;
  unsigned z = 0;
  for (int i = blockIdx.x * blockDim.x + threadIdx.x; i < TOTAL / 4; i += stride) {
    float4 f = ((const float4*)A)[i];
    unsigned u;
    u = __float_as_uint(f.x); if (u) atomicAdd(&h[u >> 20], 1u); else z++;
    u = __float_as_uint(f.y); if (u) atomicAdd(&h[u >> 20], 1u); else z++;
    u = __float_as_uint(f.z); if (u) atomicAdd(&h[u >> 20], 1u); else z++;
    u = __float_as_uint(f.w); if (u) atomicAdd(&h[u >> 20], 1u); else z++;
  }
  if (z) atomicAdd(&h[0], z);
  __syncthreads();
  for (int i = threadIdx.x; i < 2048; i += 256) if (h[i]) atomicAdd(&hist[i], h[i]);
}

// ---------------- find level 1 (single block over global 2048-bin hist) --------
__launch_bounds__(256)
__global__ void find_kernel(const unsigned* __restrict__ hist, uint2* __restrict__ ctrl,
                            float* __restrict__ thr) {
  find_in_lds(hist, 2048, 0, NK, ctrl, thr);
}

// ---- append boundary-bin elements (block-aggregated: LDS stage, 1 atomic/blk) -
// ~3000 matches total; per block ~12. LDS atomics are cheap; exactly one
// same-address global atomic per block (R13 lesson: per-match global atomics
// on one line serialize cross-XCD at ~12ns each).
__launch_bounds__(256)
__global__ void append_kernel(const float* __restrict__ A, const uint2* __restrict__ ctrl,
                              unsigned* __restrict__ buf, unsigned* __restrict__ cnt) {
  __shared__ unsigned lbuf[4096];
  __shared__ unsigned lcnt, base;
  unsigned B1 = ctrl[0].x;
  if (threadIdx.x == 0) lcnt = 0;
  __syncthreads();
  int stride = gridDim.x * blockDim.x;
  for (int i = blockIdx.x * blockDim.x + threadIdx.x; i < TOTAL / 4; i += stride) {
    float4 f = ((const float4*)A)[i];
    unsigned u;
    u = __float_as_uint(f.x);
    if ((u >> 20) == B1) { unsigned p = atomicAdd(&lcnt, 1u); if (p < 4096) lbuf[p] = u & 0xFFFFF; }
    u = __float_as_uint(f.y);
    if ((u >> 20) == B1) { unsigned p = atomicAdd(&lcnt, 1u); if (p < 4096) lbuf[p] = u & 0xFFFFF; }
    u = __float_as_uint(f.z);
    if ((u >> 20) == B1) { unsigned p = atomicAdd(&lcnt, 1u); if (p < 4096) lbuf[p] = u & 0xFFFFF; }
    u = __float_as_uint(f.w);
    if ((u >> 20) == B1) { unsigned p = atomicAdd(&lcnt, 1u); if (p < 4096) lbuf[p] = u & 0xFFFFF; }
  }
  __syncthreads();
  unsigned n = lcnt < 4096u ? lcnt : 4096u;
  if (threadIdx.x == 0) base = atomicAdd(cnt, n);
  __syncthreads();
  for (unsigned i = threadIdx.x; i < n; i += 256) {
    unsigned p = base + i;
    if (p < ACAP) buf[p] = lbuf[i];
  }
}

// ---- final select: levels 2+3 over the appended candidates (one block) --------
__launch_bounds__(256)
__global__ void findfin_kernel(const unsigned* __restrict__ buf, const unsigned* __restrict__ cnt,
                               uint2* __restrict__ ctrl, float* __restrict__ thr) {
  __shared__ unsigned h[4096];
  int t = threadIdx.x;
  for (int i = t; i < 4096; i += 256) h[i] = 0;
  __syncthreads();
  unsigned N = *cnt; if (N > ACAP) N = ACAP;
  unsigned kth1 = ctrl[0].y;
  for (unsigned i = t; i < N; i += 256) atomicAdd(&h[(buf[i] >> 8) & 0xFFF], 1u);
  __syncthreads();
  find_in_lds(h, 4096, 1, kth1, ctrl, thr);
  unsigned b2 = ctrl[1].x, kth2 = ctrl[1].y;   // thread0 wrote; trailing sync in helper
  h[t] = 0;
  __syncthreads();
  for (unsigned i = t; i < N; i += 256)
    if (((buf[i] >> 8) & 0xFFF) == b2) atomicAdd(&h[buf[i] & 0xFF], 1u);
  __syncthreads();
  find_in_lds(h, 256, 2, kth2, ctrl, thr);
}

// ---------------- per-position top-3 (one wave per position) ------------------
__launch_bounds__(256)
__global__ void top3_kernel(const float* __restrict__ A, const float* __restrict__ thrp,
                            float* __restrict__ t3v, int* __restrict__ t3i) {
  int gid = blockIdx.x * blockDim.x + threadIdx.x;
  int wid = gid >> 6, lane = gid & 63;
  float thr = *thrp;
  float4 av = *(const float4*)&A[wid * 256 + lane * 4];
  float va[4] = {av.x, av.y, av.z, av.w};
  float v0 = -1.f, v1 = -1.f, v2 = -1.f;
  int i0 = 0, i1 = 0, i2 = 0;
#pragma unroll
  for (int j = 0; j < 4; j++) {
    float val = (va[j] >= thr) ? va[j] : 0.f;
    int idx = lane * 4 + j;
    if (val > v0)      { v2 = v1; i2 = i1; v1 = v0; i1 = i0; v0 = val; i0 = idx; }
    else if (val > v1) { v2 = v1; i2 = i1; v1 = val; i1 = idx; }
    else if (val > v2) { v2 = val; i2 = idx; }
  }
#pragma unroll
  for (int off = 1; off < 64; off <<= 1) {
    float b0 = __shfl_xor(v0, off), b1 = __shfl_xor(v1, off), b2 = __shfl_xor(v2, off);
    int   j0 = __shfl_xor(i0, off), j1 = __shfl_xor(i1, off), j2 = __shfl_xor(i2, off);
    float a0 = v0, a1 = v1, a2 = v2;
    int   x0 = i0, x1 = i1, x2 = i2;
    float rv[3]; int ri[3];
#pragma unroll
    for (int r = 0; r < 3; r++) {
      bool ta = (a0 > b0) || (a0 == b0 && x0 < j0);
      rv[r] = ta ? a0 : b0; ri[r] = ta ? x0 : j0;
      if (ta) { a0 = a1; x0 = x1; a1 = a2; x1 = x2; a2 = -1.f; x2 = 1 << 29; }
      else    { b0 = b1; j0 = j1; b1 = b2; j1 = j2; b2 = -1.f; j2 = 1 << 29; }
    }
    v0 = rv[0]; v1 = rv[1]; v2 = rv[2];
    i0 = ri[0]; i1 = ri[1]; i2 = ri[2];
  }
  if (lane == 0) {
    t3v[wid * 3] = v0; t3v[wid * 3 + 1] = v1; t3v[wid * 3 + 2] = v2;
    t3i[wid * 3] = i0; t3i[wid * 3 + 1] = i1; t3i[wid * 3 + 2] = i2;
  }
}

// ------- per-batch global max from t3v (16 blocks) + pe table (same grid) -----
__launch_bounds__(256)
__global__ void gmax_kernel(const float* __restrict__ t3v, float* __restrict__ gmax,
                            float* __restrict__ pe) {
  __shared__ float wm[4];
  int b = blockIdx.x, t = threadIdx.x;
  {   // fused pe fill: 16 blocks x 256 = 4096 entries
    int id = b * 256 + t;
    int w = id >> 7, d = id & 127;
    int i = d >> 1;
    float ang = (float)w * __expf(-(float)i * (logf(10000.f) / 64.f));
    pe[id] = (d & 1) ? cosf(ang) : sinf(ang);
  }
  float m = 0.f;
#pragma unroll
  for (int i = 0; i < 4; i++) {
    int p = (b << 10) + i * 256 + t;
    m = fmaxf(m, t3v[p * 3]);
  }
#pragma unroll
  for (int off = 1; off < 64; off <<= 1) m = fmaxf(m, __shfl_xor(m, off));
  if ((t & 63) == 0) wm[t >> 6] = m;
  __syncthreads();
  if (t == 0) gmax[b] = fmaxf(fmaxf(wm[0], wm[1]), fmaxf(wm[2], wm[3]));
}

// ---------------- sparse_weights (full rows) + top_idx + loc ------------------
__launch_bounds__(256)
__global__ void scatter_loc_kernel(const float* __restrict__ t3v, const int* __restrict__ t3i,
                                   const float* __restrict__ gmax,
                                   const float* __restrict__ pe, const float* __restrict__ emb,
                                   float* __restrict__ out_sw, float* __restrict__ out_idx,
                                   float* __restrict__ loc) {
  int t = threadIdx.x;
  int p = blockIdx.x * 2 + (t >> 7);
  int d = t & 127;
  int b = p >> 10;
  float g = gmax[b];
  float denom = (g == 0.f) ? 1.f : g;
  float v0 = t3v[p * 3], v1 = t3v[p * 3 + 1];
  int i0 = t3i[p * 3], i1 = t3i[p * 3 + 1];
  float sw0 = v0 / denom, sw1 = v1 / denom;
  float a = pe[(p & 31) * 128 + d];
  if (v0 > 0.f) a += sw0 * emb[i0 * 128 + d];
  if (v1 > 0.f) a += sw1 * emb[i1 * 128 + d];
  loc[p * 128 + d] = a;
  // full sparse_weights row (zeros + the two scattered values) -> no memset
  int c = d * 2;
  float2 sw;
  sw.x = (c == i0) ? sw0 : (c == i1) ? sw1 : 0.f;
  sw.y = (c + 1 == i0) ? sw0 : (c + 1 == i1) ? sw1 : 0.f;
  *(float2*)&out_sw[(size_t)p * 256 + c] = sw;
  if (d == 0) {
    out_idx[p * 3 + 0] = (float)t3i[p * 3 + 0];
    out_idx[p * 3 + 1] = (float)t3i[p * 3 + 1];
    out_idx[p * 3 + 2] = (float)t3i[p * 3 + 2];
  }
}

// ---------------- qkv GEMM (MFMA f16): C[j][pos] = ipw . loc^T ----------------
// Q pre-scaled by 0.25*log2(e) -> attention scores land in log2 domain.
#define QSCALE 0.36067376f   // 0.25 * 1.4426950408889634
__launch_bounds__(256)
__global__ void qkv_gemm(const float* __restrict__ ipw, const float* __restrict__ loc,
                         const float* __restrict__ bias,
                         _Float16* __restrict__ Qh, _Float16* __restrict__ Kh,
                         _Float16* __restrict__ Vt) {
  __shared__ _Float16 Aw[64][136];   // [j_local][k]   272B pitch (16B-mult)
  __shared__ _Float16 Bl[64][136];   // [pos_local][k]
  __shared__ _Float16 Ts[64][72];    // V transpose [d_local][pos_local], 144B pitch
  int bid = blockIdx.x;
  int lb = (bid & 7) * 192 + (bid >> 3);       // XCD swizzle (1536 = 8*192)
  int jt = lb % 6;                   // j-tile: 0,1=Q 2,3=K 4,5=V
  int pt = lb / 6;                   // pos-tile 0..255 (64 pos, never crosses batch)
  int j0 = jt * 64, p0 = pt * 64;
  int t = threadIdx.x;
#pragma unroll
  for (int i = 0; i < 8; i++) {      // stage W tile: 64 j-rows x 128 k (f32->f16)
    int id = t + i * 256;
    int row = id >> 5, k4 = id & 31;
    float4 f = *(const float4*)&ipw[(j0 + row) * 128 + k4 * 4];
    *(fp16x4*)&Aw[row][k4 * 4] =
        (fp16x4){(_Float16)f.x, (_Float16)f.y, (_Float16)f.z, (_Float16)f.w};
  }
#pragma unroll
  for (int i = 0; i < 8; i++) {      // stage loc tile: 64 pos-rows x 128 k
    int id = t + i * 256;
    int row = id >> 5, k4 = id & 31;
    float4 f = *(const float4*)&loc[(size_t)(p0 + row) * 128 + k4 * 4];
    *(fp16x4*)&Bl[row][k4 * 4] =
        (fp16x4){(_Float16)f.x, (_Float16)f.y, (_Float16)f.z, (_Float16)f.w};
  }
  __syncthreads();
  int w = t >> 6, l = t & 63;
  int lr = l & 15, lg = l >> 4;      // lr = in-tile row/col, lg = k-group
  f32x4 acc[4] = {};                 // 4 pos-subtiles, wave owns j-sub = w*16
#pragma unroll
  for (int kk = 0; kk < 8; kk++) {
    int k0 = kk * 16 + lg * 4;
    fp16x4 a = *(const fp16x4*)&Aw[w * 16 + lr][k0];
#pragma unroll
    for (int ps = 0; ps < 4; ps++) {
      fp16x4 bf = *(const fp16x4*)&Bl[ps * 16 + lr][k0];
      acc[ps] = __builtin_amdgcn_mfma_f32_16x16x16f16(a, bf, acc[ps], 0, 0, 0);
    }
  }
  // lane holds C[j = j0 + w*16 + lg*4 + r][pos = p0 + ps*16 + lr]
  int jbase = j0 + w * 16;           // 16-aligned -> one head per wave
  int b = p0 >> 10;
  int sp = p0 & 1023;
  if (jt < 4) {
    bool isQ = (jbase < 128);
    float scale = isQ ? QSCALE : 1.f;
    _Float16* dst = isQ ? Qh : Kh;
    int head = (jbase - (isQ ? 0 : 128)) >> 4;
#pragma unroll
    for (int ps = 0; ps < 4; ps++) {
      int pos = sp + ps * 16 + lr;
      fp16x4 v;
#pragma unroll
      for (int r = 0; r < 4; r++)
        v[r] = (_Float16)((acc[ps][r] + bias[jbase + lg * 4 + r]) * scale);
      *(fp16x4*)&dst[(size_t)(((b * 8 + head) << 10) + pos) * 16 + lg * 4] = v;
    }
  } else {
    // V: scatter into Ts[d_local][pos_local], then coalesced row writes to Vt
#pragma unroll
    for (int ps = 0; ps < 4; ps++) {
#pragma unroll
      for (int r = 0; r < 4; r++)
        Ts[w * 16 + lg * 4 + r][ps * 16 + lr] =
            (_Float16)(acc[ps][r] + bias[jbase + lg * 4 + r]);
    }
    __syncthreads();
    int dl = t >> 2, seg = t & 3;
    int vcol = (j0 - 256) + dl;      // 0..127
    int head = vcol >> 4, d = vcol & 15;
    float4 w0 = *(float4*)&Ts[dl][seg * 16];
    float4 w1 = *(float4*)&Ts[dl][seg * 16 + 8];
    _Float16* dp = &Vt[(size_t)(((b * 8 + head) * 16 + d) << 10) + sp + seg * 16];
    *(float4*)dp = w0;
    *(float4*)(dp + 8) = w1;
  }
}

// ---------------- MFMA flash attention (exp2-domain, 256-key batches) ---------
// R12-measured-best structure: sc[16] deep MFMA chain, exp2, cvt_pkrtz.
#define KP 24    // Kl pitch (halves): 48B rows -> 2-way LDS (free)
#define VP 264   // Vl pitch (halves): 528B rows, 16B-aligned
__launch_bounds__(256)
__global__ void attn_kernel(const _Float16* __restrict__ Qh, const _Float16* __restrict__ Kh,
                            const _Float16* __restrict__ Vt, float* __restrict__ ctx) {
  __shared__ _Float16 Kl[256][KP];
  __shared__ _Float16 Vl[16][VP];
  int bid = blockIdx.x;
  int lb = ((bid & 7) << 8) | (bid >> 3);   // XCD swizzle: same-(b,h) on one XCD
  int qt = lb & 15;
  int h  = (lb >> 4) & 7;
  int b  = lb >> 7;
  int bh = b * 8 + h;
  int t  = threadIdx.x;
  int w  = t >> 6, l = t & 63;
  int ql = l & 15, g = l >> 4;

  int qbase = qt * 64 + w * 16;
  fp16x4 bq = *(const fp16x4*)&Qh[(size_t)((bh << 10) + qbase + ql) * 16 + g * 4];

  float m = -1e30f, lsum = 0.f;
  f32x4 acc = {0.f, 0.f, 0.f, 0.f};

  for (int kc = 0; kc < 4; ++kc) {
    __syncthreads();
    {   // stage K rows (1 key/thread, 32B) + Vt rows (d = t>>4, 16 keys/thread)
      const float4* kp = (const float4*)&Kh[(size_t)((bh << 10) + kc * 256 + t) * 16];
      float4 a0 = kp[0], a1 = kp[1];
      *(float4*)&Kl[t][0] = a0;
      *(float4*)&Kl[t][8] = a1;
      int d = t >> 4, seg = t & 15;
      const float4* vp = (const float4*)&Vt[(size_t)((bh * 16 + d) << 10) + kc * 256 + seg * 16];
      float4 b0 = vp[0], b1 = vp[1];
      *(float4*)&Vl[d][seg * 16] = b0;
      *(float4*)&Vl[d][seg * 16 + 8] = b1;
    }
    __syncthreads();
    f32x4 sc[16];
    float cm = -1e30f;
#pragma unroll
    for (int ts = 0; ts < 16; ++ts) {
      fp16x4 ka = *(const fp16x4*)&Kl[ts * 16 + ql][g * 4];
      sc[ts] = __builtin_amdgcn_mfma_f32_16x16x16f16(ka, bq,
                 (f32x4){0.f, 0.f, 0.f, 0.f}, 0, 0, 0);
      cm = fmaxf(cm, fmaxf(fmaxf(sc[ts][0], sc[ts][1]), fmaxf(sc[ts][2], sc[ts][3])));
    }
    cm = fmaxf(cm, __shfl_xor(cm, 16));
    cm = fmaxf(cm, __shfl_xor(cm, 32));
    if (!__all(cm <= m + 11.5f)) {     // defer-max, log2 units (2^11.5 ~ e^8)
      float mn = fmaxf(m, cm);
      float scl = __builtin_amdgcn_exp2f(m - mn);
      lsum *= scl;
      acc[0] *= __shfl(scl, g * 4 + 0);
      acc[1] *= __shfl(scl, g * 4 + 1);
      acc[2] *= __shfl(scl, g * 4 + 2);
      acc[3] *= __shfl(scl, g * 4 + 3);
      m = mn;
    }
#pragma unroll
    for (int ts = 0; ts < 16; ++ts) {
      float p0 = __builtin_amdgcn_exp2f(sc[ts][0] - m);
      float p1 = __builtin_amdgcn_exp2f(sc[ts][1] - m);
      float p2 = __builtin_amdgcn_exp2f(sc[ts][2] - m);
      float p3 = __builtin_amdgcn_exp2f(sc[ts][3] - m);
      lsum += (p0 + p1) + (p2 + p3);
      union { fp16r2 h2[2]; fp16x4 h4; } u;
      u.h2[0] = __builtin_amdgcn_cvt_pkrtz(p0, p1);
      u.h2[1] = __builtin_amdgcn_cvt_pkrtz(p2, p3);
      fp16x4 vb = *(const fp16x4*)&Vl[ql][ts * 16 + g * 4];
      acc = __builtin_amdgcn_mfma_f32_16x16x16f16(u.h4, vb, acc, 0, 0, 0);
    }
  }
  lsum += __shfl_xor(lsum, 16);
  lsum += __shfl_xor(lsum, 32);
  float inv = 1.f / lsum;
  float* cp = ctx + (size_t)((b << 10) + qbase) * 128 + h * 16;
#pragma unroll
  for (int r = 0; r < 4; ++r) {    // acc[r]: q = 4g+r, d = ql
    float o = acc[r] * __shfl(inv, g * 4 + r);
    cp[(g * 4 + r) * 128 + ql] = o;
  }
}

// ---------------- mean over sequence + out_proj -------------------------------
__launch_bounds__(128)
__global__ void mean_kernel(const float* __restrict__ ctx, float* __restrict__ cmean) {
  int b = blockIdx.x >> 3, sc = blockIdx.x & 7, d = threadIdx.x;
  float s = 0.f;
  for (int i = 0; i < 128; i++) s += ctx[((b << 10) + sc * 128 + i) * 128 + d];
  atomicAdd(&cmean[b * 128 + d], s);
}

__launch_bounds__(256)
__global__ void pooled_kernel(const float* __restrict__ cm, const float* __restrict__ W,
                              const float* __restrict__ bias, float* __restrict__ out) {
  int id = blockIdx.x * 256 + threadIdx.x;   // 2048
  int b = id >> 7, d = id & 127;
  float s = bias[d];
  const float sc = 1.f / 1024.f;
  for (int k = 0; k < 128; k++) s += cm[b * 128 + k] * sc * W[d * 128 + k];
  out[id] = s;
}

extern "C" void kernel_launch(void* const* d_in, const int* in_sizes, int n_in,
                              void* d_out, int out_size, void* d_ws, size_t ws_size,
                              hipStream_t stream) {
  (void)in_sizes; (void)n_in; (void)out_size;
  if (ws_size < 34400000) return;   // need ~34.3 MB scratch

  const float* x   = (const float*)d_in[0];
  const float* cw  = (const float*)d_in[1];
  const float* emb = (const float*)d_in[2];
  const float* ipw = (const float*)d_in[3];
  const float* ipb = (const float*)d_in[4];
  const float* opw = (const float*)d_in[5];
  const float* opb = (const float*)d_in[6];

  char* ws = (char*)d_ws;
  float*     A    = (float*)(ws + 0);           // 16.78 MB, dead after top3
  _Float16*  Vt   = (_Float16*)(ws + 0);        // 4.19 MB, overwrites A
  float*     ctx  = (float*)(ws + 4194304);     // 8.39 MB (after top3)
  float*     loc  = (float*)(ws + 16777216);    // 8.39 MB
  _Float16*  Qh   = (_Float16*)(ws + 25165824); // 4.19 MB (after radix phase)
  unsigned*  abuf = (unsigned*)(ws + 25165824); // 4 MB append buffer (radix phase only)
  _Float16*  Kh   = (_Float16*)(ws + 29360128); // 4.19 MB
  char* ctrlb = ws + 33554432;                 // 64 KB control block (memset 0)
  unsigned* h1    = (unsigned*)(ctrlb);
  uint2*    ctrl  = (uint2*)(ctrlb + 25600);
  float*    thr   = (float*)(ctrlb + 25632);
  float*    gmax  = (float*)(ctrlb + 25664);
  float*    cmean = (float*)(ctrlb + 25728);
  unsigned* acnt  = (unsigned*)(ctrlb + 33920);
  float* pe  = (float*)(ws + 33554432 + 65536);
  float* t3v = (float*)(ws + 33554432 + 65536 + 16384);
  int*   t3i = (int*)  (ws + 33554432 + 65536 + 16384 + 196608);

  float* out_pooled = (float*)d_out;                   // 2048
  float* out_sw     = out_pooled + 2048;               // 4194304 (fully written)
  float* out_idx    = out_pooled + 2048 + 4194304;     // 49152  (fully written)

  hipMemsetAsync(ctrlb, 0, 65536, stream);

  conv_kernel<<<512, 256, 0, stream>>>(x, cw, A);
  hist1_kernel<<<256, 256, 0, stream>>>(A, h1);
  find_kernel<<<1, 256, 0, stream>>>(h1, ctrl, thr);
  append_kernel<<<256, 256, 0, stream>>>(A, ctrl, abuf, acnt);
  findfin_kernel<<<1, 256, 0, stream>>>(abuf, acnt, ctrl, thr);
  top3_kernel<<<4096, 256, 0, stream>>>(A, thr, t3v, t3i);
  gmax_kernel<<<16, 256, 0, stream>>>(t3v, gmax, pe);
  scatter_loc_kernel<<<8192, 256, 0, stream>>>(t3v, t3i, gmax, pe, emb, out_sw, out_idx, loc);
  qkv_gemm<<<1536, 256, 0, stream>>>(ipw, loc, ipb, Qh, Kh, Vt);
  attn_kernel<<<2048, 256, 0, stream>>>(Qh, Kh, Vt, ctx);
  mean_kernel<<<128, 128, 0, stream>>>(ctx, cmean);
  pooled_kernel<<<8, 256, 0, stream>>>(cmean, opw, opb, out_pooled);
}

// Round 15
// 190.646 us; speedup vs baseline: 1.1158x; 1.0066x over previous
//
#include <hip/hip_runtime.h>
#include <hip/hip_bf16.h>

#define TOTAL   4194304    // 16*256*32*32
#define NK      2098u      // ceil(0.0005*TOTAL)
#define NPOS    16384      // 16*32*32
#define ACAP    1048576u   // append buffer capacity (4 MB region)

typedef _Float16 fp16x4 __attribute__((ext_vector_type(4)));
typedef __fp16   fp16r2 __attribute__((ext_vector_type(2)));   // cvt_pkrtz return type
typedef float    f32x4  __attribute__((ext_vector_type(4)));

// Schraudolph fast exp2: ~±3% rel err. x clamped so cvt never goes negative-int.
__device__ __forceinline__ float fexp2(float x) {
  x = fmaxf(x, -126.f);
  int i = (int)__builtin_fmaf(x, 8388608.f, 1064866808.f);  // 2^23, (127<<23)-486408
  return __int_as_float(i);
}

// ---- shared find: k-th largest over a histogram (suffix-sum radix pick) ------
// Ends with __syncthreads(); ctrl may be LDS or global; thr only used at level 2.
__device__ __forceinline__ void find_in_lds(const unsigned* h, int nbins, int level,
                                            unsigned kth, uint2* ctrl, float* thr) {
  __shared__ unsigned part[256];
  __shared__ int sel;
  int t = threadIdx.x;
  int per = nbins >> 8;
  unsigned s = 0;
  for (int i = 0; i < per; i++) s += h[t * per + i];
  part[t] = s;
  __syncthreads();
  for (int off = 1; off < 256; off <<= 1) {
    unsigned add = (t + off < 256) ? part[t + off] : 0u;
    __syncthreads();
    part[t] += add;
    __syncthreads();
  }
  if ((part[t] >= kth) && (t == 255 || part[t + 1] < kth)) sel = t;
  __syncthreads();
  if (t == 0) {
    int c = sel;
    unsigned cum = (c < 255) ? part[c + 1] : 0u;
    for (int i = per - 1; i >= 0; --i) {
      unsigned hv = h[c * per + i];
      if (cum + hv >= kth) {
        ctrl[level].x = (unsigned)(c * per + i);
        ctrl[level].y = kth - cum;
        break;
      }
      cum += hv;
    }
    if (level == 2) {
      unsigned bits = (ctrl[0].x << 20) | (ctrl[1].x << 8) | ctrl[2].x;
      *thr = __uint_as_float(bits);
    }
  }
  __syncthreads();
}

// ---------------- conv 9x9, 1->256ch, ReLU, output A[b][y*32+x][c] -------------
__launch_bounds__(256)
__global__ void conv_kernel(const float* __restrict__ x, const float* __restrict__ w,
                            float* __restrict__ A) {
  int b = blockIdx.x >> 5;      // 16
  int y = blockIdx.x & 31;      // 32
  int c = threadIdx.x;          // 256
  const float* xb = x + b * 1024;
  const float* wc = w + c * 81;
  float acc[32];
#pragma unroll
  for (int i = 0; i < 32; i++) acc[i] = 0.f;
#pragma unroll
  for (int dy = 0; dy < 9; ++dy) {
    int yy = y + dy - 4;
    if (yy < 0 || yy >= 32) continue;      // uniform per block
    float wv[9];
#pragma unroll
    for (int dx = 0; dx < 9; ++dx) wv[dx] = wc[dy * 9 + dx];
    const float* xr = xb + yy * 32;
#pragma unroll
    for (int ix = 0; ix < 32; ++ix) {
      float xv = xr[ix];                   // uniform -> scalar load
#pragma unroll
      for (int dx = 0; dx < 9; ++dx) {
        int ox = ix + 4 - dx;
        if (ox >= 0 && ox < 32) acc[ox] += wv[dx] * xv;
      }
    }
  }
  float* Arow = A + ((b * 32 + y) * 32) * 256 + c;
#pragma unroll
  for (int ox = 0; ox < 32; ++ox) {
    float v = acc[ox] > 0.f ? acc[ox] : 0.f;
    Arow[ox * 256] = v;
  }
}

// ---------------- level-1 histogram (2048 exponent bins, LDS-staged) -----------
__launch_bounds__(256)
__global__ void hist1_kernel(const float* __restrict__ A, unsigned* __restrict__ hist) {
  __shared__ unsigned h[2048];
  for (int i = threadIdx.x; i < 2048; i += 256) h[i] = 0;
  __syncthreads();
  int stride = gridDim.x * blockDim.x;
  unsigned z = 0;
  for (int i = blockIdx.x * blockDim.x + threadIdx.x; i < TOTAL / 4; i += stride) {
    float4 f = ((const float4*)A)[i];
    unsigned u;
    u = __float_as_uint(f.x); if (u) atomicAdd(&h[u >> 20], 1u); else z++;
    u = __float_as_uint(f.y); if (u) atomicAdd(&h[u >> 20], 1u); else z++;
    u = __float_as_uint(f.z); if (u) atomicAdd(&h[u >> 20], 1u); else z++;
    u = __float_as_uint(f.w); if (u) atomicAdd(&h[u >> 20], 1u); else z++;
  }
  if (z) atomicAdd(&h[0], z);
  __syncthreads();
  for (int i = threadIdx.x; i < 2048; i += 256) if (h[i]) atomicAdd(&hist[i], h[i]);
}

// ---- append boundary-bin elements; level-1 find done inline (per block) -------
// Each block redundantly computes (B1, kth1) from the global hist (deterministic,
// ~L2-resident); block 0 publishes ctrl[0] for findfin. Matches staged in LDS,
// ONE global atomic per block (R13 lesson: per-match same-line atomics serialize).
__launch_bounds__(256)
__global__ void append_kernel(const float* __restrict__ A, const unsigned* __restrict__ hist,
                              unsigned* __restrict__ buf, unsigned* __restrict__ cnt,
                              uint2* __restrict__ gctrl) {
  __shared__ uint2 lctrl[1];
  __shared__ unsigned lbuf[4096];
  __shared__ unsigned lcnt, base;
  if (threadIdx.x == 0) lcnt = 0;
  find_in_lds(hist, 2048, 0, NK, lctrl, nullptr);   // ends with syncthreads
  unsigned B1 = lctrl[0].x;
  if (blockIdx.x == 0 && threadIdx.x == 0) gctrl[0] = lctrl[0];
  int stride = gridDim.x * blockDim.x;
  for (int i = blockIdx.x * blockDim.x + threadIdx.x; i < TOTAL / 4; i += stride) {
    float4 f = ((const float4*)A)[i];
    unsigned u;
    u = __float_as_uint(f.x);
    if ((u >> 20) == B1) { unsigned p = atomicAdd(&lcnt, 1u); if (p < 4096) lbuf[p] = u & 0xFFFFF; }
    u = __float_as_uint(f.y);
    if ((u >> 20) == B1) { unsigned p = atomicAdd(&lcnt, 1u); if (p < 4096) lbuf[p] = u & 0xFFFFF; }
    u = __float_as_uint(f.z);
    if ((u >> 20) == B1) { unsigned p = atomicAdd(&lcnt, 1u); if (p < 4096) lbuf[p] = u & 0xFFFFF; }
    u = __float_as_uint(f.w);
    if ((u >> 20) == B1) { unsigned p = atomicAdd(&lcnt, 1u); if (p < 4096) lbuf[p] = u & 0xFFFFF; }
  }
  __syncthreads();
  unsigned n = lcnt < 4096u ? lcnt : 4096u;
  if (threadIdx.x == 0) base = atomicAdd(cnt, n);
  __syncthreads();
  for (unsigned i = threadIdx.x; i < n; i += 256) {
    unsigned p = base + i;
    if (p < ACAP) buf[p] = lbuf[i];
  }
}

// ---- final select: levels 2+3 over the appended candidates (one block) --------
__launch_bounds__(256)
__global__ void findfin_kernel(const unsigned* __restrict__ buf, const unsigned* __restrict__ cnt,
                               uint2* __restrict__ ctrl, float* __restrict__ thr) {
  __shared__ unsigned h[4096];
  int t = threadIdx.x;
  for (int i = t; i < 4096; i += 256) h[i] = 0;
  __syncthreads();
  unsigned N = *cnt; if (N > ACAP) N = ACAP;
  unsigned kth1 = ctrl[0].y;
  for (unsigned i = t; i < N; i += 256) atomicAdd(&h[(buf[i] >> 8) & 0xFFF], 1u);
  __syncthreads();
  find_in_lds(h, 4096, 1, kth1, ctrl, thr);
  unsigned b2 = ctrl[1].x, kth2 = ctrl[1].y;   // thread0 wrote; trailing sync in helper
  h[t] = 0;
  __syncthreads();
  for (unsigned i = t; i < N; i += 256)
    if (((buf[i] >> 8) & 0xFFF) == b2) atomicAdd(&h[buf[i] & 0xFF], 1u);
  __syncthreads();
  find_in_lds(h, 256, 2, kth2, ctrl, thr);
}

// ---------------- per-position top-3 (one wave per position) ------------------
__launch_bounds__(256)
__global__ void top3_kernel(const float* __restrict__ A, const float* __restrict__ thrp,
                            float* __restrict__ t3v, int* __restrict__ t3i) {
  int gid = blockIdx.x * blockDim.x + threadIdx.x;
  int wid = gid >> 6, lane = gid & 63;
  float thr = *thrp;
  float4 av = *(const float4*)&A[wid * 256 + lane * 4];
  float va[4] = {av.x, av.y, av.z, av.w};
  float v0 = -1.f, v1 = -1.f, v2 = -1.f;
  int i0 = 0, i1 = 0, i2 = 0;
#pragma unroll
  for (int j = 0; j < 4; j++) {
    float val = (va[j] >= thr) ? va[j] : 0.f;
    int idx = lane * 4 + j;
    if (val > v0)      { v2 = v1; i2 = i1; v1 = v0; i1 = i0; v0 = val; i0 = idx; }
    else if (val > v1) { v2 = v1; i2 = i1; v1 = val; i1 = idx; }
    else if (val > v2) { v2 = val; i2 = idx; }
  }
#pragma unroll
  for (int off = 1; off < 64; off <<= 1) {
    float b0 = __shfl_xor(v0, off), b1 = __shfl_xor(v1, off), b2 = __shfl_xor(v2, off);
    int   j0 = __shfl_xor(i0, off), j1 = __shfl_xor(i1, off), j2 = __shfl_xor(i2, off);
    float a0 = v0, a1 = v1, a2 = v2;
    int   x0 = i0, x1 = i1, x2 = i2;
    float rv[3]; int ri[3];
#pragma unroll
    for (int r = 0; r < 3; r++) {
      bool ta = (a0 > b0) || (a0 == b0 && x0 < j0);
      rv[r] = ta ? a0 : b0; ri[r] = ta ? x0 : j0;
      if (ta) { a0 = a1; x0 = x1; a1 = a2; x1 = x2; a2 = -1.f; x2 = 1 << 29; }
      else    { b0 = b1; j0 = j1; b1 = b2; j1 = j2; b2 = -1.f; j2 = 1 << 29; }
    }
    v0 = rv[0]; v1 = rv[1]; v2 = rv[2];
    i0 = ri[0]; i1 = ri[1]; i2 = ri[2];
  }
  if (lane == 0) {
    t3v[wid * 3] = v0; t3v[wid * 3 + 1] = v1; t3v[wid * 3 + 2] = v2;
    t3i[wid * 3] = i0; t3i[wid * 3 + 1] = i1; t3i[wid * 3 + 2] = i2;
  }
}

// ------- per-batch global max from t3v (16 blocks) + pe table (same grid) -----
__launch_bounds__(256)
__global__ void gmax_kernel(const float* __restrict__ t3v, float* __restrict__ gmax,
                            float* __restrict__ pe) {
  __shared__ float wm[4];
  int b = blockIdx.x, t = threadIdx.x;
  {   // fused pe fill: 16 blocks x 256 = 4096 entries
    int id = b * 256 + t;
    int w = id >> 7, d = id & 127;
    int i = d >> 1;
    float ang = (float)w * __expf(-(float)i * (logf(10000.f) / 64.f));
    pe[id] = (d & 1) ? cosf(ang) : sinf(ang);
  }
  float m = 0.f;
#pragma unroll
  for (int i = 0; i < 4; i++) {
    int p = (b << 10) + i * 256 + t;
    m = fmaxf(m, t3v[p * 3]);
  }
#pragma unroll
  for (int off = 1; off < 64; off <<= 1) m = fmaxf(m, __shfl_xor(m, off));
  if ((t & 63) == 0) wm[t >> 6] = m;
  __syncthreads();
  if (t == 0) gmax[b] = fmaxf(fmaxf(wm[0], wm[1]), fmaxf(wm[2], wm[3]));
}

// ---------------- sparse_weights (full rows) + top_idx + loc ------------------
__launch_bounds__(256)
__global__ void scatter_loc_kernel(const float* __restrict__ t3v, const int* __restrict__ t3i,
                                   const float* __restrict__ gmax,
                                   const float* __restrict__ pe, const float* __restrict__ emb,
                                   float* __restrict__ out_sw, float* __restrict__ out_idx,
                                   float* __restrict__ loc) {
  int t = threadIdx.x;
  int p = blockIdx.x * 2 + (t >> 7);
  int d = t & 127;
  int b = p >> 10;
  float g = gmax[b];
  float denom = (g == 0.f) ? 1.f : g;
  float v0 = t3v[p * 3], v1 = t3v[p * 3 + 1];
  int i0 = t3i[p * 3], i1 = t3i[p * 3 + 1];
  float sw0 = v0 / denom, sw1 = v1 / denom;
  float a = pe[(p & 31) * 128 + d];
  if (v0 > 0.f) a += sw0 * emb[i0 * 128 + d];
  if (v1 > 0.f) a += sw1 * emb[i1 * 128 + d];
  loc[p * 128 + d] = a;
  // full sparse_weights row (zeros + the two scattered values) -> no memset
  int c = d * 2;
  float2 sw;
  sw.x = (c == i0) ? sw0 : (c == i1) ? sw1 : 0.f;
  sw.y = (c + 1 == i0) ? sw0 : (c + 1 == i1) ? sw1 : 0.f;
  *(float2*)&out_sw[(size_t)p * 256 + c] = sw;
  if (d == 0) {
    out_idx[p * 3 + 0] = (float)t3i[p * 3 + 0];
    out_idx[p * 3 + 1] = (float)t3i[p * 3 + 1];
    out_idx[p * 3 + 2] = (float)t3i[p * 3 + 2];
  }
}

// ---------------- qkv GEMM (MFMA f16): C[j][pos] = ipw . loc^T ----------------
// Q pre-scaled by 0.25*log2(e) -> attention scores land in log2 domain.
#define QSCALE 0.36067376f   // 0.25 * 1.4426950408889634
__launch_bounds__(256)
__global__ void qkv_gemm(const float* __restrict__ ipw, const float* __restrict__ loc,
                         const float* __restrict__ bias,
                         _Float16* __restrict__ Qh, _Float16* __restrict__ Kh,
                         _Float16* __restrict__ Vt) {
  __shared__ _Float16 Aw[64][136];   // [j_local][k]   272B pitch (16B-mult)
  __shared__ _Float16 Bl[64][136];   // [pos_local][k]
  __shared__ _Float16 Ts[64][72];    // V transpose [d_local][pos_local], 144B pitch
  int bid = blockIdx.x;
  int lb = (bid & 7) * 192 + (bid >> 3);       // XCD swizzle (1536 = 8*192)
  int jt = lb % 6;                   // j-tile: 0,1=Q 2,3=K 4,5=V
  int pt = lb / 6;                   // pos-tile 0..255 (64 pos, never crosses batch)
  int j0 = jt * 64, p0 = pt * 64;
  int t = threadIdx.x;
#pragma unroll
  for (int i = 0; i < 8; i++) {      // stage W tile: 64 j-rows x 128 k (f32->f16)
    int id = t + i * 256;
    int row = id >> 5, k4 = id & 31;
    float4 f = *(const float4*)&ipw[(j0 + row) * 128 + k4 * 4];
    *(fp16x4*)&Aw[row][k4 * 4] =
        (fp16x4){(_Float16)f.x, (_Float16)f.y, (_Float16)f.z, (_Float16)f.w};
  }
#pragma unroll
  for (int i = 0; i < 8; i++) {      // stage loc tile: 64 pos-rows x 128 k
    int id = t + i * 256;
    int row = id >> 5, k4 = id & 31;
    float4 f = *(const float4*)&loc[(size_t)(p0 + row) * 128 + k4 * 4];
    *(fp16x4*)&Bl[row][k4 * 4] =
        (fp16x4){(_Float16)f.x, (_Float16)f.y, (_Float16)f.z, (_Float16)f.w};
  }
  __syncthreads();
  int w = t >> 6, l = t & 63;
  int lr = l & 15, lg = l >> 4;      // lr = in-tile row/col, lg = k-group
  f32x4 acc[4] = {};                 // 4 pos-subtiles, wave owns j-sub = w*16
#pragma unroll
  for (int kk = 0; kk < 8; kk++) {
    int k0 = kk * 16 + lg * 4;
    fp16x4 a = *(const fp16x4*)&Aw[w * 16 + lr][k0];
#pragma unroll
    for (int ps = 0; ps < 4; ps++) {
      fp16x4 bf = *(const fp16x4*)&Bl[ps * 16 + lr][k0];
      acc[ps] = __builtin_amdgcn_mfma_f32_16x16x16f16(a, bf, acc[ps], 0, 0, 0);
    }
  }
  // lane holds C[j = j0 + w*16 + lg*4 + r][pos = p0 + ps*16 + lr]
  int jbase = j0 + w * 16;           // 16-aligned -> one head per wave
  int b = p0 >> 10;
  int sp = p0 & 1023;
  if (jt < 4) {
    bool isQ = (jbase < 128);
    float scale = isQ ? QSCALE : 1.f;
    _Float16* dst = isQ ? Qh : Kh;
    int head = (jbase - (isQ ? 0 : 128)) >> 4;
#pragma unroll
    for (int ps = 0; ps < 4; ps++) {
      int pos = sp + ps * 16 + lr;
      fp16x4 v;
#pragma unroll
      for (int r = 0; r < 4; r++)
        v[r] = (_Float16)((acc[ps][r] + bias[jbase + lg * 4 + r]) * scale);
      *(fp16x4*)&dst[(size_t)(((b * 8 + head) << 10) + pos) * 16 + lg * 4] = v;
    }
  } else {
    // V: scatter into Ts[d_local][pos_local], then coalesced row writes to Vt
#pragma unroll
    for (int ps = 0; ps < 4; ps++) {
#pragma unroll
      for (int r = 0; r < 4; r++)
        Ts[w * 16 + lg * 4 + r][ps * 16 + lr] =
            (_Float16)(acc[ps][r] + bias[jbase + lg * 4 + r]);
    }
    __syncthreads();
    int dl = t >> 2, seg = t & 3;
    int vcol = (j0 - 256) + dl;      // 0..127
    int head = vcol >> 4, d = vcol & 15;
    float4 w0 = *(float4*)&Ts[dl][seg * 16];
    float4 w1 = *(float4*)&Ts[dl][seg * 16 + 8];
    _Float16* dp = &Vt[(size_t)(((b * 8 + head) * 16 + d) << 10) + sp + seg * 16];
    *(float4*)dp = w0;
    *(float4*)(dp + 8) = w1;
  }
}

// ---------------- MFMA flash attention (fast-exp2, 256-key batches) -----------
// Scores in log2 domain (Q pre-scaled by 0.25*log2e). P-loop uses Schraudolph
// fexp2 (3 full-rate ops vs 16-cyc quarter-rate v_exp). Rescale path exact.
#define KP 24    // Kl pitch (halves): 48B rows -> 2-way LDS (free)
#define VP 264   // Vl pitch (halves): 528B rows, 16B-aligned
__launch_bounds__(256)
__global__ void attn_kernel(const _Float16* __restrict__ Qh, const _Float16* __restrict__ Kh,
                            const _Float16* __restrict__ Vt, float* __restrict__ ctx) {
  __shared__ _Float16 Kl[256][KP];
  __shared__ _Float16 Vl[16][VP];
  int bid = blockIdx.x;
  int lb = ((bid & 7) << 8) | (bid >> 3);   // XCD swizzle: same-(b,h) on one XCD
  int qt = lb & 15;
  int h  = (lb >> 4) & 7;
  int b  = lb >> 7;
  int bh = b * 8 + h;
  int t  = threadIdx.x;
  int w  = t >> 6, l = t & 63;
  int ql = l & 15, g = l >> 4;

  int qbase = qt * 64 + w * 16;
  fp16x4 bq = *(const fp16x4*)&Qh[(size_t)((bh << 10) + qbase + ql) * 16 + g * 4];

  float m = -1e30f, lsum = 0.f;
  f32x4 acc = {0.f, 0.f, 0.f, 0.f};

  for (int kc = 0; kc < 4; ++kc) {
    __syncthreads();
    {   // stage K rows (1 key/thread, 32B) + Vt rows (d = t>>4, 16 keys/thread)
      const float4* kp = (const float4*)&Kh[(size_t)((bh << 10) + kc * 256 + t) * 16];
      float4 a0 = kp[0], a1 = kp[1];
      *(float4*)&Kl[t][0] = a0;
      *(float4*)&Kl[t][8] = a1;
      int d = t >> 4, seg = t & 15;
      const float4* vp = (const float4*)&Vt[(size_t)((bh * 16 + d) << 10) + kc * 256 + seg * 16];
      float4 b0 = vp[0], b1 = vp[1];
      *(float4*)&Vl[d][seg * 16] = b0;
      *(float4*)&Vl[d][seg * 16 + 8] = b1;
    }
    __syncthreads();
    f32x4 sc[16];
    float cm = -1e30f;
#pragma unroll
    for (int ts = 0; ts < 16; ++ts) {
      fp16x4 ka = *(const fp16x4*)&Kl[ts * 16 + ql][g * 4];
      sc[ts] = __builtin_amdgcn_mfma_f32_16x16x16f16(ka, bq,
                 (f32x4){0.f, 0.f, 0.f, 0.f}, 0, 0, 0);
      cm = fmaxf(cm, fmaxf(fmaxf(sc[ts][0], sc[ts][1]), fmaxf(sc[ts][2], sc[ts][3])));
    }
    cm = fmaxf(cm, __shfl_xor(cm, 16));
    cm = fmaxf(cm, __shfl_xor(cm, 32));
    if (!__all(cm <= m + 11.5f)) {     // defer-max, log2 units (2^11.5 ~ e^8)
      float mn = fmaxf(m, cm);
      float scl = __builtin_amdgcn_exp2f(m - mn);
      lsum *= scl;
      acc[0] *= __shfl(scl, g * 4 + 0);
      acc[1] *= __shfl(scl, g * 4 + 1);
      acc[2] *= __shfl(scl, g * 4 + 2);
      acc[3] *= __shfl(scl, g * 4 + 3);
      m = mn;
    }
#pragma unroll
    for (int ts = 0; ts < 16; ++ts) {
      float p0 = fexp2(sc[ts][0] - m);
      float p1 = fexp2(sc[ts][1] - m);
      float p2 = fexp2(sc[ts][2] - m);
      float p3 = fexp2(sc[ts][3] - m);
      lsum += (p0 + p1) + (p2 + p3);
      union { fp16r2 h2[2]; fp16x4 h4; } u;
      u.h2[0] = __builtin_amdgcn_cvt_pkrtz(p0, p1);
      u.h2[1] = __builtin_amdgcn_cvt_pkrtz(p2, p3);
      fp16x4 vb = *(const fp16x4*)&Vl[ql][ts * 16 + g * 4];
      acc = __builtin_amdgcn_mfma_f32_16x16x16f16(u.h4, vb, acc, 0, 0, 0);
    }
  }
  lsum += __shfl_xor(lsum, 16);
  lsum += __shfl_xor(lsum, 32);
  float inv = 1.f / lsum;
  float* cp = ctx + (size_t)((b << 10) + qbase) * 128 + h * 16;
#pragma unroll
  for (int r = 0; r < 4; ++r) {    // acc[r]: q = 4g+r, d = ql
    float o = acc[r] * __shfl(inv, g * 4 + r);
    cp[(g * 4 + r) * 128 + ql] = o;
  }
}

// ---------------- mean over sequence + out_proj -------------------------------
__launch_bounds__(128)
__global__ void mean_kernel(const float* __restrict__ ctx, float* __restrict__ cmean) {
  int b = blockIdx.x >> 3, sc = blockIdx.x & 7, d = threadIdx.x;
  float s = 0.f;
  for (int i = 0; i < 128; i++) s += ctx[((b << 10) + sc * 128 + i) * 128 + d];
  atomicAdd(&cmean[b * 128 + d], s);
}

__launch_bounds__(256)
__global__ void pooled_kernel(const float* __restrict__ cm, const float* __restrict__ W,
                              const float* __restrict__ bias, float* __restrict__ out) {
  int id = blockIdx.x * 256 + threadIdx.x;   // 2048
  int b = id >> 7, d = id & 127;
  float s = bias[d];
  const float sc = 1.f / 1024.f;
  for (int k = 0; k < 128; k++) s += cm[b * 128 + k] * sc * W[d * 128 + k];
  out[id] = s;
}

extern "C" void kernel_launch(void* const* d_in, const int* in_sizes, int n_in,
                              void* d_out, int out_size, void* d_ws, size_t ws_size,
                              hipStream_t stream) {
  (void)in_sizes; (void)n_in; (void)out_size;
  if (ws_size < 34400000) return;   // need ~34.3 MB scratch

  const float* x   = (const float*)d_in[0];
  const float* cw  = (const float*)d_in[1];
  const float* emb = (const float*)d_in[2];
  const float* ipw = (const float*)d_in[3];
  const float* ipb = (const float*)d_in[4];
  const float* opw = (const float*)d_in[5];
  const float* opb = (const float*)d_in[6];

  char* ws = (char*)d_ws;
  float*     A    = (float*)(ws + 0);           // 16.78 MB, dead after top3
  _Float16*  Vt   = (_Float16*)(ws + 0);        // 4.19 MB, overwrites A
  float*     ctx  = (float*)(ws + 4194304);     // 8.39 MB (after top3)
  float*     loc  = (float*)(ws + 16777216);    // 8.39 MB
  _Float16*  Qh   = (_Float16*)(ws + 25165824); // 4.19 MB (after radix phase)
  unsigned*  abuf = (unsigned*)(ws + 25165824); // 4 MB append buffer (radix phase only)
  _Float16*  Kh   = (_Float16*)(ws + 29360128); // 4.19 MB
  char* ctrlb = ws + 33554432;                 // 64 KB control block (memset 0)
  unsigned* h1    = (unsigned*)(ctrlb);
  uint2*    ctrl  = (uint2*)(ctrlb + 25600);
  float*    thr   = (float*)(ctrlb + 25632);
  float*    gmax  = (float*)(ctrlb + 25664);
  float*    cmean = (float*)(ctrlb + 25728);
  unsigned* acnt  = (unsigned*)(ctrlb + 33920);
  float* pe  = (float*)(ws + 33554432 + 65536);
  float* t3v = (float*)(ws + 33554432 + 65536 + 16384);
  int*   t3i = (int*)  (ws + 33554432 + 65536 + 16384 + 196608);

  float* out_pooled = (float*)d_out;                   // 2048
  float* out_sw     = out_pooled + 2048;               // 4194304 (fully written)
  float* out_idx    = out_pooled + 2048 + 4194304;     // 49152  (fully written)

  hipMemsetAsync(ctrlb, 0, 65536, stream);

  conv_kernel<<<512, 256, 0, stream>>>(x, cw, A);
  hist1_kernel<<<256, 256, 0, stream>>>(A, h1);
  append_kernel<<<256, 256, 0, stream>>>(A, h1, abuf, acnt, ctrl);
  findfin_kernel<<<1, 256, 0, stream>>>(abuf, acnt, ctrl, thr);
  top3_kernel<<<4096, 256, 0, stream>>>(A, thr, t3v, t3i);
  gmax_kernel<<<16, 256, 0, stream>>>(t3v, gmax, pe);
  scatter_loc_kernel<<<8192, 256, 0, stream>>>(t3v, t3i, gmax, pe, emb, out_sw, out_idx, loc);
  qkv_gemm<<<1536, 256, 0, stream>>>(ipw, loc, ipb, Qh, Kh, Vt);
  attn_kernel<<<2048, 256, 0, stream>>>(Qh, Kh, Vt, ctx);
  mean_kernel<<<128, 128, 0, stream>>>(ctx, cmean);
  pooled_kernel<<<8, 256, 0, stream>>>(cmean, opw, opb, out_pooled);
}